// Round 10
// baseline (243.657 us; speedup 1.0000x reference)
//
#include <hip/hip_runtime.h>
#include <hip/hip_bf16.h>
#include <cstdint>

#define N_SPK 1024
#define M_UTT 20
#define D_DIM 768
#define NM_ROWS (N_SPK * M_UTT)   // 20480 utterances / rows

static constexpr float EPS = 1e-8f;

// s_waitcnt immediates (gfx9): vmcnt[3:0]=bits3:0, expcnt=6:4, lgkmcnt=11:8,
// vmcnt[5:4]=bits15:14.
#define WAIT_VM0   0x0F70   // vmcnt=0,  lgkm/exp no-wait
#define WAIT_VM8   0x0F78   // vmcnt=8,  lgkm/exp no-wait
#define WAIT_LGKM0 0xC07F   // lgkmcnt=0, vmcnt/exp no-wait

typedef __attribute__((ext_vector_type(4))) float floatx4;  // MFMA accumulator
typedef __attribute__((ext_vector_type(4))) int   intx4;    // 16B load/LDS op
typedef __attribute__((ext_vector_type(8))) int   intx8;    // 32B MFMA operand

__device__ __forceinline__ void load16_to_lds(const void* g, void* l) {
    __builtin_amdgcn_global_load_lds(
        (const __attribute__((address_space(1))) uint32_t*)g,
        (__attribute__((address_space(3))) uint32_t*)l, 16, 0, 0);
}

__device__ __forceinline__ float wave_sum(float v) {
    #pragma unroll
    for (int o = 32; o > 0; o >>= 1) v += __shfl_xor(v, o);
    return v;
}

// pack two f32 -> two OCP e4m3 bytes (low word of result)
__device__ __forceinline__ unsigned short fp8pk(float a, float b) {
    return (unsigned short)(__builtin_amdgcn_cvt_pk_fp8_f32(a, b, 0, false) & 0xFFFF);
}

// K-interleave permutation (prep-time, within each 64-byte K-block). Applied
// identically to ehat and chat; the gemm reads both operands through identical
// k-addressing, so this global k-bijection cancels in the MFMA dot product
// (validated empirically: absmax 0.0 in R5-R9).
__device__ __forceinline__ int kperm(int d) {
    return (d & ~63) | (((d >> 3) & 3) << 4) | (((d >> 5) & 1) << 3) | (d & 7);
}

// ---------------------------------------------------------------------------
// Kernel 1 (prep): per speaker, read emb once (float2/thread, 384 thr),
// centroid + 20 utterance norms; write FP8 e4m3 Ehat ([m][i][dp]) and Chat.
// Zero-inits ctr/accum.  (unchanged — isolate the gemm change)
// ---------------------------------------------------------------------------
__global__ __launch_bounds__(384) void prep_kernel(const float* __restrict__ emb,
                                                   unsigned char* __restrict__ ehat,
                                                   unsigned char* __restrict__ chat,
                                                   int* __restrict__ ctr,
                                                   float* __restrict__ accum) {
    const int i = blockIdx.x;      // speaker
    const int t = threadIdx.x;     // 0..383
    const int wave = t >> 6, lane = t & 63;

    if (i == 0 && t == 0) { *ctr = 0; *accum = 0.f; }

    const float2* src = (const float2*)(emb + (size_t)i * M_UTT * D_DIM);
    const int dp = kperm(t * 2);   // byte index of the fp8 pair in stored layout

    float2 v[M_UTT];
    float ss[M_UTT];
    float2 cen = {0.f, 0.f};
    #pragma unroll
    for (int m = 0; m < M_UTT; ++m) {
        const float2 x = src[m * 384 + t];
        v[m] = x;
        ss[m] = x.x * x.x + x.y * x.y;
        cen.x += x.x; cen.y += x.y;
    }
    cen.x *= (1.f / M_UTT); cen.y *= (1.f / M_UTT);
    float css = cen.x * cen.x + cen.y * cen.y;

    __shared__ float red[M_UTT + 1][6];
    #pragma unroll
    for (int m = 0; m < M_UTT; ++m) {
        const float s = wave_sum(ss[m]);
        if (lane == 0) red[m][wave] = s;
    }
    {
        const float s = wave_sum(css);
        if (lane == 0) red[M_UTT][wave] = s;
    }
    __syncthreads();

    #pragma unroll
    for (int m = 0; m < M_UTT; ++m) {
        const float tot = red[m][0] + red[m][1] + red[m][2] +
                          red[m][3] + red[m][4] + red[m][5];
        const float rn = 1.0f / fmaxf(sqrtf(tot), EPS);
        *(unsigned short*)(ehat + ((size_t)(m * N_SPK + i)) * D_DIM + dp) =
            fp8pk(v[m].x * rn, v[m].y * rn);
    }
    {
        const float tot = red[M_UTT][0] + red[M_UTT][1] + red[M_UTT][2] +
                          red[M_UTT][3] + red[M_UTT][4] + red[M_UTT][5];
        const float rn = 1.0f / fmaxf(sqrtf(tot), EPS);
        *(unsigned short*)(chat + (size_t)i * D_DIM + dp) =
            fp8pk(cen.x * rn, cen.y * rn);
    }
}

// ---------------------------------------------------------------------------
// Kernel 2 (R10): 256x256 tile, 512 threads = 8 waves (4x2 of 64x128 each),
// BK=128, 6 K-iters, MX-scaled fp8 MFMA.
//   Traffic law (R1/R5-R8): gemm time ~ staged bytes / 9 TB/s, invariant to
//   everything else tried. This tile halves staged bytes: 252 -> 126 MB
//   (320 blocks x (192+192 KB)); grid 320 = 1.25 generations.
//   - A: gld_lds double-buffer 2x32 KB.  B: single 32 KB buffer, reg-staged
//     (R8/R9-proven write-late chain; absmax 0.0 twice).
//   - LDS 96 KB -> 1 block/CU, 8 waves (2/SIMD).
//   - VGPR (the R9 lesson): 512 thr halves staging regs -> live set approx
//     acc 128 + av 32 + bv 32 (grouped by 4 cols) + breg 16 + addr ~15 = 223
//     under the 256 budget of __launch_bounds__(512,2). WRITE_SIZE is the
//     spill canary (must stay ~1.4 MB).
//   - Pacing: tail ds_write's reg-dep drains B(kt+1) loads (and A(kt+1),
//     issued earlier in that tail); top-of-loop vm8 = exact in-flight count
//     (A(kt+2) 4 + B(kt+2) 4); vmcnt(0) only at kt=5.
// Psum geometry unchanged: rb320 = bu*4 + wr covers 0..319.
// ---------------------------------------------------------------------------
__global__ __launch_bounds__(512, 2) void gemm_fused_kernel(
        const unsigned char* __restrict__ ehat,
        const unsigned char* __restrict__ chat,
        const float* __restrict__ wp,
        float* __restrict__ Psum,
        float* __restrict__ T) {
    __shared__ unsigned char As[2][256 * 128];   // 2 x 32 KB (A dbuf)
    __shared__ unsigned char Bs[256 * 128];      // 32 KB (B single buffer)

    const int t    = threadIdx.x;      // 0..511
    const int lane = t & 63;
    const int c    = lane & 15;
    const int quad = lane >> 4;
    const int wid  = t >> 6;           // 0..7
    const int wr   = wid >> 1;         // row quadrant 0..3 (64 rows each)
    const int wc   = wid & 1;          // col half 0..1 (128 cols each)

    const int xcd = blockIdx.x & 7;
    const int idx = blockIdx.x >> 3;        // 0..39 per XCD
    const int bu  = xcd * 10 + (idx >> 2);  // 0..79 (256-row tiles)
    const int bj  = idx & 3;                // 0..3  (256-col tiles)
    const int m   = bu >> 2;                // 4 bu-tiles per m-slab
    const int rb4 = bu & 3;
    const int u0  = bu * 256;
    const int j0  = bj * 256;

    const unsigned char* Ag = ehat + (size_t)u0 * D_DIM;
    const unsigned char* Bg = chat + (size_t)j0 * D_DIM;

    // Staging: each tile = 2048 16B chunks; thread covers ci = s*512 + t,
    // s=0..3 (rows step 64: swizzle (row&7) invariant). Dest LINEAR at ci*16.
    const int row0  = t >> 3;                                        // 0..63
    const int goff0 = row0 * D_DIM + (((t & 7) ^ (row0 & 7)) * 16);  // A pre-swz src
    const int boff0 = row0 * D_DIM + ((t & 7) * 16);                 // B linear src
    const int bdst0 = row0 * 128 + (((t & 7) ^ (row0 & 7)) * 16);    // B swz LDS dst

    // Fragment bases: lane wants logical chunks {quad, quad+4} of its row;
    // phys0 = quad ^ (c&7); second 16B at addr ^ 64.
    const int sw     = (quad ^ (c & 7)) * 16;
    const int slotA0 = (wr * 64 + c) * 128 + sw;    // + f*2048,  f =0..3
    const int slotB0 = (wc * 128 + c) * 128 + sw;   // + jt*2048, jt=0..7

    floatx4 acc[4][8] = {};   // 128 regs (AGPR side)
    intx4 breg[4];

    // ---- prologue: A(0),A(1) gld_lds; B(0) reg->LDS; breg <- B(1).
    #pragma unroll
    for (int s = 0; s < 4; ++s)
        load16_to_lds(Ag + goff0 + s * 64 * D_DIM,       &As[0][s * 8192 + t * 16]);
    #pragma unroll
    for (int s = 0; s < 4; ++s)
        load16_to_lds(Ag + goff0 + s * 64 * D_DIM + 128, &As[1][s * 8192 + t * 16]);
    #pragma unroll
    for (int s = 0; s < 4; ++s)
        breg[s] = *(const intx4*)(Bg + boff0 + s * 64 * D_DIM);          // B(0)
    #pragma unroll
    for (int s = 0; s < 4; ++s)
        *(intx4*)(&Bs[bdst0 + s * 8192]) = breg[s];   // reg-dep drains A(0),A(1),B(0)
    #pragma unroll
    for (int s = 0; s < 4; ++s)
        breg[s] = *(const intx4*)(Bg + boff0 + s * 64 * D_DIM + 128);    // B(1)
    __builtin_amdgcn_s_waitcnt(WAIT_LGKM0);
    __builtin_amdgcn_sched_barrier(0);
    __builtin_amdgcn_s_barrier();             // tile 0 ready
    __builtin_amdgcn_sched_barrier(0);

    #pragma unroll
    for (int kt = 0; kt < 6; ++kt) {
        const int cur = kt & 1;

        if (kt > 0) {
            // steady in-flight = A(kt+1) 4 + B(kt+1) 4; older tiles drained
            // by the previous tail's ds_write reg-dependency.
            if (kt < 5) __builtin_amdgcn_s_waitcnt(WAIT_VM8);
            else        __builtin_amdgcn_s_waitcnt(WAIT_VM0);
            __builtin_amdgcn_s_waitcnt(WAIT_LGKM0);   // B ds_writes visible
            __builtin_amdgcn_sched_barrier(0);
            __builtin_amdgcn_s_barrier();             // tile kt ready everywhere
            __builtin_amdgcn_sched_barrier(0);
        }

        intx8 av[4];
        #pragma unroll
        for (int f = 0; f < 4; ++f) {
            const int sa = slotA0 + f * 2048;
            const intx4 lo = *(const intx4*)(&As[cur][sa]);
            const intx4 hi = *(const intx4*)(&As[cur][sa ^ 64]);
            av[f] = __builtin_shufflevector(lo, hi, 0, 1, 2, 3, 4, 5, 6, 7);
        }
        #pragma unroll
        for (int g = 0; g < 2; ++g) {          // jt in 2 groups of 4 (VGPR cap)
            intx8 bv[4];
            #pragma unroll
            for (int j = 0; j < 4; ++j) {
                const int sb = slotB0 + (g * 4 + j) * 2048;
                const intx4 lo = *(const intx4*)(&Bs[sb]);
                const intx4 hi = *(const intx4*)(&Bs[sb ^ 64]);
                bv[j] = __builtin_shufflevector(lo, hi, 0, 1, 2, 3, 4, 5, 6, 7);
            }
            __builtin_amdgcn_s_setprio(1);
            #pragma unroll
            for (int it = 0; it < 4; ++it)
                #pragma unroll
                for (int j = 0; j < 4; ++j)
                    acc[it][g * 4 + j] = __builtin_amdgcn_mfma_scale_f32_16x16x128_f8f6f4(
                        av[it], bv[j], acc[it][g * 4 + j],
                        0, 0,                      // cbsz/blgp = fp8 e4m3
                        0, 0x7F7F7F7F,             // A scales: e8m0 1.0
                        0, 0x7F7F7F7F);            // B scales: e8m0 1.0
            __builtin_amdgcn_s_setprio(0);
        }

        if (kt < 5) {
            // WAR: all waves' ds_reads of As[cur]/Bs retired before reuse.
            __builtin_amdgcn_s_waitcnt(WAIT_LGKM0);
            __builtin_amdgcn_sched_barrier(0);
            __builtin_amdgcn_s_barrier();
            __builtin_amdgcn_sched_barrier(0);
            const int k0 = (kt + 2) * 128;
            if (kt < 4) {
                #pragma unroll
                for (int s = 0; s < 4; ++s)
                    load16_to_lds(Ag + goff0 + s * 64 * D_DIM + k0,
                                  &As[cur][s * 8192 + t * 16]);
            }
            // write B(kt+1) -> Bs; reg-dep drains B(kt+1) loads and A(kt+1)
            // (issued earlier) — the pipeline's pacing wait.
            #pragma unroll
            for (int s = 0; s < 4; ++s)
                *(intx4*)(&Bs[bdst0 + s * 8192]) = breg[s];
            if (kt < 4) {
                #pragma unroll
                for (int s = 0; s < 4; ++s)
                    breg[s] = *(const intx4*)(Bg + boff0 + s * 64 * D_DIM + k0);
            }
            __builtin_amdgcn_sched_barrier(0);
        }
    }

    const float w = wp[0];
    const int rb320 = bu * 4 + wr;      // 64-row block index, 0..319

    // per-column fixed-offset partial: sum exp(w*(cos-1)) over the wave's 64 rows
    #pragma unroll
    for (int jt = 0; jt < 8; ++jt) {
        float sm = 0.f;
        #pragma unroll
        for (int it = 0; it < 4; ++it)
            #pragma unroll
            for (int r = 0; r < 4; ++r)
                sm += __expf(w * (acc[it][jt][r] - 1.0f));
        sm += __shfl_xor(sm, 16);
        sm += __shfl_xor(sm, 32);
        if (quad == 0)
            Psum[(size_t)rb320 * N_SPK + j0 + wc * 128 + jt * 16 + c] = sm;
    }

    // target sims: local row within m-slab == (m*1024+col)/20 (unique owner)
    #pragma unroll
    for (int it = 0; it < 4; ++it) {
        #pragma unroll
        for (int jt = 0; jt < 8; ++jt) {
            const int col = j0 + wc * 128 + jt * 16 + c;
            const int g = m * N_SPK + col;
            const int istar = g / M_UTT;
            const int rloc = rb4 * 256 + wr * 64 + it * 16 + quad * 4;
            #pragma unroll
            for (int r = 0; r < 4; ++r) {
                if (rloc + r == istar) T[g] = acc[it][jt][r];
            }
        }
    }
}

// ---------------------------------------------------------------------------
// Kernel 3: combine 16 row-block partials per (m,j) -> loss term; block sum;
// last-block writes output (ctr/accum zeroed by prep).
// term = (w*T+b) - ((w+b) + log S) = w*(T-1) - log S.
// ---------------------------------------------------------------------------
__global__ void combine_kernel(const float* __restrict__ Psum,
                               const float* __restrict__ T,
                               const float* __restrict__ wp,
                               int* __restrict__ ctr,
                               float* __restrict__ accum,
                               float* __restrict__ out) {
    const int p = blockIdx.x * 256 + threadIdx.x;
    const int m = p >> 10;
    const int j = p & 1023;
    const float w = wp[0];

    float S = 0.f;
    #pragma unroll
    for (int rb = 0; rb < 16; ++rb)
        S += Psum[(size_t)(m * 16 + rb) * N_SPK + j];
    const float term = w * (T[p] - 1.0f) - __logf(S);

    __shared__ float red[256];
    red[threadIdx.x] = term;
    __syncthreads();
    for (int o = 128; o > 0; o >>= 1) {
        if (threadIdx.x < o) red[threadIdx.x] += red[threadIdx.x + o];
        __syncthreads();
    }
    if (threadIdx.x == 0) {
        atomicAdd(accum, red[0]);
        __threadfence();
        const int old = atomicAdd(ctr, 1);
        if (old == 79) {
            const float a = atomicAdd(accum, 0.0f);   // coherent read
            out[0] = -a / (float)NM_ROWS;
        }
    }
}

// ---------------------------------------------------------------------------
extern "C" void kernel_launch(void* const* d_in, const int* in_sizes, int n_in,
                              void* d_out, int out_size, void* d_ws, size_t ws_size,
                              hipStream_t stream) {
    const float* emb = (const float*)d_in[0];
    const float* wp  = (const float*)d_in[1];
    float* out = (float*)d_out;

    char* ws = (char*)d_ws;
    //   Ehat fp8 [M][N][D] : 15,728,640  @ 0
    //   Chat fp8 [N][D]    :    786,432  @ 15,728,640
    //   Psum f32 [320][N]  :  1,310,720  @ 16,515,072
    //   T    f32 [M][N]    :     81,920  @ 17,825,792
    //   ctr i32 + accum f32:          8  @ 17,907,712
    unsigned char* ehat = (unsigned char*)(ws);
    unsigned char* chat = (unsigned char*)(ws + 15728640);
    float* Psum  = (float*)(ws + 16515072);
    float* T     = (float*)(ws + 17825792);
    int*   ctr   = (int*)  (ws + 17907712);
    float* accum = (float*)(ws + 17907716);

    prep_kernel<<<dim3(N_SPK), dim3(384), 0, stream>>>(emb, ehat, chat, ctr, accum);
    gemm_fused_kernel<<<dim3(320), dim3(512), 0, stream>>>(ehat, chat, wp, Psum, T);
    combine_kernel<<<dim3(80), dim3(256), 0, stream>>>(Psum, T, wp, ctr, accum, out);
}

// Round 11
// 234.151 us; speedup vs baseline: 1.0406x; 1.0406x over previous
//
#include <hip/hip_runtime.h>
#include <hip/hip_bf16.h>
#include <cstdint>

#define N_SPK 1024
#define M_UTT 20
#define D_DIM 768
#define NM_ROWS (N_SPK * M_UTT)   // 20480 utterances / rows

static constexpr float EPS = 1e-8f;

// s_waitcnt immediates (gfx9): vmcnt[3:0]=bits3:0, expcnt=6:4, lgkmcnt=11:8,
// vmcnt[5:4]=bits15:14.
#define WAIT_VM0   0x0F70   // vmcnt=0,  lgkm/exp no-wait
#define WAIT_VM8   0x0F78   // vmcnt=8,  lgkm/exp no-wait
#define WAIT_LGKM0 0xC07F   // lgkmcnt=0, vmcnt/exp no-wait

typedef __attribute__((ext_vector_type(4))) float floatx4;  // MFMA accumulator
typedef __attribute__((ext_vector_type(4))) int   intx4;    // 16B LDS read
typedef __attribute__((ext_vector_type(8))) int   intx8;    // 32B MFMA operand

__device__ __forceinline__ void load16_to_lds(const void* g, void* l) {
    __builtin_amdgcn_global_load_lds(
        (const __attribute__((address_space(1))) uint32_t*)g,
        (__attribute__((address_space(3))) uint32_t*)l, 16, 0, 0);
}

__device__ __forceinline__ float wave_sum(float v) {
    #pragma unroll
    for (int o = 32; o > 0; o >>= 1) v += __shfl_xor(v, o);
    return v;
}

// pack two f32 -> two OCP e4m3 bytes (low word of result)
__device__ __forceinline__ unsigned short fp8pk(float a, float b) {
    return (unsigned short)(__builtin_amdgcn_cvt_pk_fp8_f32(a, b, 0, false) & 0xFFFF);
}

// K-interleave permutation (prep-time, within each 64-byte K-block). Applied
// identically to ehat and chat; the gemm reads both operands through identical
// k-addressing, so this global k-bijection cancels in the MFMA dot product
// (validated empirically: absmax 0.0 in R5-R10).
__device__ __forceinline__ int kperm(int d) {
    return (d & ~63) | (((d >> 3) & 3) << 4) | (((d >> 5) & 1) << 3) | (d & 7);
}

// ---------------------------------------------------------------------------
// Kernel 1 (prep): per speaker, read emb once (float2/thread, 384 thr),
// centroid + 20 utterance norms; write FP8 e4m3 Ehat ([m][i][dp]) and Chat.
// Zero-inits ctr/accum.  (unchanged — isolate the gemm change)
// ---------------------------------------------------------------------------
__global__ __launch_bounds__(384) void prep_kernel(const float* __restrict__ emb,
                                                   unsigned char* __restrict__ ehat,
                                                   unsigned char* __restrict__ chat,
                                                   int* __restrict__ ctr,
                                                   float* __restrict__ accum) {
    const int i = blockIdx.x;      // speaker
    const int t = threadIdx.x;     // 0..383
    const int wave = t >> 6, lane = t & 63;

    if (i == 0 && t == 0) { *ctr = 0; *accum = 0.f; }

    const float2* src = (const float2*)(emb + (size_t)i * M_UTT * D_DIM);
    const int dp = kperm(t * 2);   // byte index of the fp8 pair in stored layout

    float2 v[M_UTT];
    float ss[M_UTT];
    float2 cen = {0.f, 0.f};
    #pragma unroll
    for (int m = 0; m < M_UTT; ++m) {
        const float2 x = src[m * 384 + t];
        v[m] = x;
        ss[m] = x.x * x.x + x.y * x.y;
        cen.x += x.x; cen.y += x.y;
    }
    cen.x *= (1.f / M_UTT); cen.y *= (1.f / M_UTT);
    float css = cen.x * cen.x + cen.y * cen.y;

    __shared__ float red[M_UTT + 1][6];
    #pragma unroll
    for (int m = 0; m < M_UTT; ++m) {
        const float s = wave_sum(ss[m]);
        if (lane == 0) red[m][wave] = s;
    }
    {
        const float s = wave_sum(css);
        if (lane == 0) red[M_UTT][wave] = s;
    }
    __syncthreads();

    #pragma unroll
    for (int m = 0; m < M_UTT; ++m) {
        const float tot = red[m][0] + red[m][1] + red[m][2] +
                          red[m][3] + red[m][4] + red[m][5];
        const float rn = 1.0f / fmaxf(sqrtf(tot), EPS);
        *(unsigned short*)(ehat + ((size_t)(m * N_SPK + i)) * D_DIM + dp) =
            fp8pk(v[m].x * rn, v[m].y * rn);
    }
    {
        const float tot = red[M_UTT][0] + red[M_UTT][1] + red[M_UTT][2] +
                          red[M_UTT][3] + red[M_UTT][4] + red[M_UTT][5];
        const float rn = 1.0f / fmaxf(sqrtf(tot), EPS);
        *(unsigned short*)(chat + (size_t)i * D_DIM + dp) =
            fp8pk(cen.x * rn, cen.y * rn);
    }
}

// ---------------------------------------------------------------------------
// Kernel 2 (R11): 256x256 tile, 512 threads = 8 waves (4x2 of 64x128),
// BK=128, 6 K-iters, MX-scaled fp8.
//   R10 spilled because B reg-staging (breg+ds_write+addressing) didn't fit
//   beside acc[4][8]=128 AGPR at the 256-reg budget. Fix: BOTH operands on
//   gld_lds, BOTH double-buffered — no reg staging at all.
//   - LDS 4 x 32 KB = 128 KB -> 1 block/CU, 8 waves (2/SIMD, same as R6).
//   - VGPR: av 32 + bv 32 + addr ~25 = ~96 arch + 128 acc = ~224 < 256.
//   - Staged traffic halves vs R6: 252 -> 126 MB (320 blocks x 384 KB);
//     grid 320 = 1.25 generations.
//   - Schedule = R7's proven counted-vmcnt constants (8 loads/tile/thread):
//     prologue stages tiles 0,1; per iter top: vmcnt(8)+barrier (tile kt in
//     LDS, kt+1 in flight); compute; lgkm0+barrier (WAR); stage kt+2.
//     vmcnt(0) only at kt=5. absmax-0-validated pattern.
// Epilogue: rb320 = bu*4 + wr (R10's, numerically verified).
// ---------------------------------------------------------------------------
__global__ __launch_bounds__(512, 2) void gemm_fused_kernel(
        const unsigned char* __restrict__ ehat,
        const unsigned char* __restrict__ chat,
        const float* __restrict__ wp,
        float* __restrict__ Psum,
        float* __restrict__ T) {
    __shared__ unsigned char As[2][256 * 128];   // 2 x 32 KB
    __shared__ unsigned char Bs[2][256 * 128];   // 2 x 32 KB

    const int t    = threadIdx.x;      // 0..511
    const int lane = t & 63;
    const int c    = lane & 15;
    const int quad = lane >> 4;
    const int wid  = t >> 6;           // 0..7
    const int wr   = wid >> 1;         // row quadrant 0..3 (64 rows each)
    const int wc   = wid & 1;          // col half 0..1 (128 cols each)

    const int xcd = blockIdx.x & 7;
    const int idx = blockIdx.x >> 3;        // 0..39 per XCD
    const int bu  = xcd * 10 + (idx >> 2);  // 0..79 (256-row tiles)
    const int bj  = idx & 3;                // 0..3  (256-col tiles)
    const int m   = bu >> 2;                // 4 bu-tiles per m-slab
    const int rb4 = bu & 3;
    const int u0  = bu * 256;
    const int j0  = bj * 256;

    const unsigned char* Ag = ehat + (size_t)u0 * D_DIM;
    const unsigned char* Bg = chat + (size_t)j0 * D_DIM;

    // Staging: tile = 2048 16B chunks; thread covers ci = s*512 + t, s=0..3
    // (rows step 64; swizzle (row&7) invariant). Dest LINEAR at ci*16; the
    // global source chunk is pre-swizzled (same for A and B — symmetric).
    const int row0  = t >> 3;                                        // 0..63
    const int goff0 = row0 * D_DIM + (((t & 7) ^ (row0 & 7)) * 16);

    // Fragment bases: lane wants logical chunks {quad, quad+4} of its row;
    // phys0 = quad ^ (c&7); second 16B at addr ^ 64.
    const int sw     = (quad ^ (c & 7)) * 16;
    const int slotA0 = (wr * 64 + c) * 128 + sw;    // + f*2048,  f =0..3
    const int slotB0 = (wc * 128 + c) * 128 + sw;   // + jt*2048, jt=0..7

    floatx4 acc[4][8] = {};   // 128 accumulator regs

    // ---- prologue: stage tiles 0 and 1 (A+B interleaved: 8 loads per tile)
    #pragma unroll
    for (int s = 0; s < 4; ++s) {
        load16_to_lds(Ag + goff0 + s * 64 * D_DIM, &As[0][s * 8192 + t * 16]);
        load16_to_lds(Bg + goff0 + s * 64 * D_DIM, &Bs[0][s * 8192 + t * 16]);
    }
    #pragma unroll
    for (int s = 0; s < 4; ++s) {
        load16_to_lds(Ag + goff0 + s * 64 * D_DIM + 128, &As[1][s * 8192 + t * 16]);
        load16_to_lds(Bg + goff0 + s * 64 * D_DIM + 128, &Bs[1][s * 8192 + t * 16]);
    }
    __builtin_amdgcn_s_waitcnt(WAIT_VM8);     // tile 0 landed; tile 1 in flight
    __builtin_amdgcn_sched_barrier(0);
    __builtin_amdgcn_s_barrier();
    __builtin_amdgcn_sched_barrier(0);

    #pragma unroll
    for (int kt = 0; kt < 6; ++kt) {
        const int cur = kt & 1;

        if (kt > 0) {
            // tile kt's 8 loads are the oldest; tile kt+1's 8 stay in flight
            if (kt < 5) __builtin_amdgcn_s_waitcnt(WAIT_VM8);
            else        __builtin_amdgcn_s_waitcnt(WAIT_VM0);
            __builtin_amdgcn_sched_barrier(0);
            __builtin_amdgcn_s_barrier();     // all threads: tile kt in LDS
            __builtin_amdgcn_sched_barrier(0);
        }

        intx8 av[4];
        #pragma unroll
        for (int f = 0; f < 4; ++f) {
            const int sa = slotA0 + f * 2048;
            const intx4 lo = *(const intx4*)(&As[cur][sa]);
            const intx4 hi = *(const intx4*)(&As[cur][sa ^ 64]);
            av[f] = __builtin_shufflevector(lo, hi, 0, 1, 2, 3, 4, 5, 6, 7);
        }
        #pragma unroll
        for (int g = 0; g < 2; ++g) {          // jt in 2 groups of 4 (VGPR cap)
            intx8 bv[4];
            #pragma unroll
            for (int j = 0; j < 4; ++j) {
                const int sb = slotB0 + (g * 4 + j) * 2048;
                const intx4 lo = *(const intx4*)(&Bs[cur][sb]);
                const intx4 hi = *(const intx4*)(&Bs[cur][sb ^ 64]);
                bv[j] = __builtin_shufflevector(lo, hi, 0, 1, 2, 3, 4, 5, 6, 7);
            }
            __builtin_amdgcn_s_setprio(1);
            #pragma unroll
            for (int it = 0; it < 4; ++it)
                #pragma unroll
                for (int j = 0; j < 4; ++j)
                    acc[it][g * 4 + j] = __builtin_amdgcn_mfma_scale_f32_16x16x128_f8f6f4(
                        av[it], bv[j], acc[it][g * 4 + j],
                        0, 0,                      // cbsz/blgp = fp8 e4m3
                        0, 0x7F7F7F7F,             // A scales: e8m0 1.0
                        0, 0x7F7F7F7F);            // B scales: e8m0 1.0
            __builtin_amdgcn_s_setprio(0);
        }

        if (kt < 4) {
            // WAR: all waves' ds_reads of buf[cur] retired before reuse.
            __builtin_amdgcn_s_waitcnt(WAIT_LGKM0);
            __builtin_amdgcn_sched_barrier(0);
            __builtin_amdgcn_s_barrier();
            __builtin_amdgcn_sched_barrier(0);
            const int k0 = (kt + 2) * 128;
            #pragma unroll
            for (int s = 0; s < 4; ++s) {
                load16_to_lds(Ag + goff0 + s * 64 * D_DIM + k0,
                              &As[cur][s * 8192 + t * 16]);
                load16_to_lds(Bg + goff0 + s * 64 * D_DIM + k0,
                              &Bs[cur][s * 8192 + t * 16]);
            }
            __builtin_amdgcn_sched_barrier(0);
        }
    }

    const float w = wp[0];
    const int rb320 = bu * 4 + wr;      // 64-row block index, 0..319

    // per-column fixed-offset partial: sum exp(w*(cos-1)) over the wave's 64 rows
    #pragma unroll
    for (int jt = 0; jt < 8; ++jt) {
        float sm = 0.f;
        #pragma unroll
        for (int it = 0; it < 4; ++it)
            #pragma unroll
            for (int r = 0; r < 4; ++r)
                sm += __expf(w * (acc[it][jt][r] - 1.0f));
        sm += __shfl_xor(sm, 16);
        sm += __shfl_xor(sm, 32);
        if (quad == 0)
            Psum[(size_t)rb320 * N_SPK + j0 + wc * 128 + jt * 16 + c] = sm;
    }

    // target sims: local row within m-slab == (m*1024+col)/20 (unique owner)
    #pragma unroll
    for (int it = 0; it < 4; ++it) {
        #pragma unroll
        for (int jt = 0; jt < 8; ++jt) {
            const int col = j0 + wc * 128 + jt * 16 + c;
            const int g = m * N_SPK + col;
            const int istar = g / M_UTT;
            const int rloc = rb4 * 256 + wr * 64 + it * 16 + quad * 4;
            #pragma unroll
            for (int r = 0; r < 4; ++r) {
                if (rloc + r == istar) T[g] = acc[it][jt][r];
            }
        }
    }
}

// ---------------------------------------------------------------------------
// Kernel 3: combine 16 row-block partials per (m,j) -> loss term; block sum;
// last-block writes output (ctr/accum zeroed by prep).
// term = (w*T+b) - ((w+b) + log S) = w*(T-1) - log S.
// ---------------------------------------------------------------------------
__global__ void combine_kernel(const float* __restrict__ Psum,
                               const float* __restrict__ T,
                               const float* __restrict__ wp,
                               int* __restrict__ ctr,
                               float* __restrict__ accum,
                               float* __restrict__ out) {
    const int p = blockIdx.x * 256 + threadIdx.x;
    const int m = p >> 10;
    const int j = p & 1023;
    const float w = wp[0];

    float S = 0.f;
    #pragma unroll
    for (int rb = 0; rb < 16; ++rb)
        S += Psum[(size_t)(m * 16 + rb) * N_SPK + j];
    const float term = w * (T[p] - 1.0f) - __logf(S);

    __shared__ float red[256];
    red[threadIdx.x] = term;
    __syncthreads();
    for (int o = 128; o > 0; o >>= 1) {
        if (threadIdx.x < o) red[threadIdx.x] += red[threadIdx.x + o];
        __syncthreads();
    }
    if (threadIdx.x == 0) {
        atomicAdd(accum, red[0]);
        __threadfence();
        const int old = atomicAdd(ctr, 1);
        if (old == 79) {
            const float a = atomicAdd(accum, 0.0f);   // coherent read
            out[0] = -a / (float)NM_ROWS;
        }
    }
}

// ---------------------------------------------------------------------------
extern "C" void kernel_launch(void* const* d_in, const int* in_sizes, int n_in,
                              void* d_out, int out_size, void* d_ws, size_t ws_size,
                              hipStream_t stream) {
    const float* emb = (const float*)d_in[0];
    const float* wp  = (const float*)d_in[1];
    float* out = (float*)d_out;

    char* ws = (char*)d_ws;
    //   Ehat fp8 [M][N][D] : 15,728,640  @ 0
    //   Chat fp8 [N][D]    :    786,432  @ 15,728,640
    //   Psum f32 [320][N]  :  1,310,720  @ 16,515,072
    //   T    f32 [M][N]    :     81,920  @ 17,825,792
    //   ctr i32 + accum f32:          8  @ 17,907,712
    unsigned char* ehat = (unsigned char*)(ws);
    unsigned char* chat = (unsigned char*)(ws + 15728640);
    float* Psum  = (float*)(ws + 16515072);
    float* T     = (float*)(ws + 17825792);
    int*   ctr   = (int*)  (ws + 17907712);
    float* accum = (float*)(ws + 17907716);

    prep_kernel<<<dim3(N_SPK), dim3(384), 0, stream>>>(emb, ehat, chat, ctr, accum);
    gemm_fused_kernel<<<dim3(320), dim3(512), 0, stream>>>(ehat, chat, wp, Psum, T);
    combine_kernel<<<dim3(80), dim3(256), 0, stream>>>(Psum, T, wp, ctr, accum, out);
}

// Round 12
// 148.599 us; speedup vs baseline: 1.6397x; 1.5757x over previous
//
#include <hip/hip_runtime.h>
#include <hip/hip_bf16.h>
#include <cstdint>

#define N_SPK 1024
#define M_UTT 20
#define D_DIM 768
#define NM_ROWS (N_SPK * M_UTT)   // 20480 utterances / rows

static constexpr float EPS = 1e-8f;

// s_waitcnt immediates (gfx9): vmcnt[3:0]=bits3:0, expcnt=6:4, lgkmcnt=11:8,
// vmcnt[5:4]=bits15:14.
#define WAIT_VM0   0x0F70   // vmcnt=0,  lgkm/exp no-wait
#define WAIT_VM8   0x0F78   // vmcnt=8,  lgkm/exp no-wait
#define WAIT_LGKM0 0xC07F   // lgkmcnt=0, vmcnt/exp no-wait

typedef __attribute__((ext_vector_type(4))) float floatx4;  // MFMA accumulator

__device__ __forceinline__ void load16_to_lds(const void* g, void* l) {
    __builtin_amdgcn_global_load_lds(
        (const __attribute__((address_space(1))) uint32_t*)g,
        (__attribute__((address_space(3))) uint32_t*)l, 16, 0, 0);
}

__device__ __forceinline__ float wave_sum(float v) {
    #pragma unroll
    for (int o = 32; o > 0; o >>= 1) v += __shfl_xor(v, o);
    return v;
}

// pack two f32 -> two OCP e4m3 bytes (low word of result)
__device__ __forceinline__ unsigned short fp8pk(float a, float b) {
    return (unsigned short)(__builtin_amdgcn_cvt_pk_fp8_f32(a, b, 0, false) & 0xFFFF);
}

// K-interleave permutation (prep-time, within each 64-byte K-block). Applied
// identically to ehat and chat; the gemm reads both operands through identical
// k-addressing, so this global k-bijection cancels in the MFMA dot product
// (validated empirically: absmax 0.0 in R5-R11).
__device__ __forceinline__ int kperm(int d) {
    return (d & ~63) | (((d >> 3) & 3) << 4) | (((d >> 5) & 1) << 3) | (d & 7);
}

// ---------------------------------------------------------------------------
// Kernel 1 (prep): per speaker, read emb once (float2/thread, 384 thr),
// centroid + 20 utterance norms; write FP8 e4m3 Ehat ([m][i][dp]) and Chat.
// Zero-inits ctr/accum.  (unchanged — isolate the gemm change)
// ---------------------------------------------------------------------------
__global__ __launch_bounds__(384) void prep_kernel(const float* __restrict__ emb,
                                                   unsigned char* __restrict__ ehat,
                                                   unsigned char* __restrict__ chat,
                                                   int* __restrict__ ctr,
                                                   float* __restrict__ accum) {
    const int i = blockIdx.x;      // speaker
    const int t = threadIdx.x;     // 0..383
    const int wave = t >> 6, lane = t & 63;

    if (i == 0 && t == 0) { *ctr = 0; *accum = 0.f; }

    const float2* src = (const float2*)(emb + (size_t)i * M_UTT * D_DIM);
    const int dp = kperm(t * 2);   // byte index of the fp8 pair in stored layout

    float2 v[M_UTT];
    float ss[M_UTT];
    float2 cen = {0.f, 0.f};
    #pragma unroll
    for (int m = 0; m < M_UTT; ++m) {
        const float2 x = src[m * 384 + t];
        v[m] = x;
        ss[m] = x.x * x.x + x.y * x.y;
        cen.x += x.x; cen.y += x.y;
    }
    cen.x *= (1.f / M_UTT); cen.y *= (1.f / M_UTT);
    float css = cen.x * cen.x + cen.y * cen.y;

    __shared__ float red[M_UTT + 1][6];
    #pragma unroll
    for (int m = 0; m < M_UTT; ++m) {
        const float s = wave_sum(ss[m]);
        if (lane == 0) red[m][wave] = s;
    }
    {
        const float s = wave_sum(css);
        if (lane == 0) red[M_UTT][wave] = s;
    }
    __syncthreads();

    #pragma unroll
    for (int m = 0; m < M_UTT; ++m) {
        const float tot = red[m][0] + red[m][1] + red[m][2] +
                          red[m][3] + red[m][4] + red[m][5];
        const float rn = 1.0f / fmaxf(sqrtf(tot), EPS);
        *(unsigned short*)(ehat + ((size_t)(m * N_SPK + i)) * D_DIM + dp) =
            fp8pk(v[m].x * rn, v[m].y * rn);
    }
    {
        const float tot = red[M_UTT][0] + red[M_UTT][1] + red[M_UTT][2] +
                          red[M_UTT][3] + red[M_UTT][4] + red[M_UTT][5];
        const float rn = 1.0f / fmaxf(sqrtf(tot), EPS);
        *(unsigned short*)(chat + (size_t)i * D_DIM + dp) =
            fp8pk(cen.x * rn, cen.y * rn);
    }
}

// ---------------------------------------------------------------------------
// Kernel 2 (R12): 256x256 tile, 512 threads = 8 waves (4x2 of 64x128),
// BK=128, 6 K-iters.  R11 geometry/schedule kept EXACTLY; compute switched
// to non-scaled mfma_f32_16x16x32_fp8_fp8 (long operands, 2 VGPR each):
// per k-subtile live set = af 8 + bf 16 = 24 arch VGPRs (vs ~96-130 for the
// scaled intx8 path that spilled in R9/R10/R11). acc[4][8]=128 AGPR + ~70
// arch < the 128 arch half of the 256 budget -> no spill.
//   - k-subtile ks reads 8B at (slot ^ (ks>>1)*64) + (ks&1)*8: lane's logical
//     chunks {quad, quad+4} split into 4x8B; A/B symmetric => sum of 4
//     sub-MFMAs == the K=128 dot (R0-R5-proven consumption pattern).
//   - Both operands gld_lds, both dbuf: LDS 128 KB, 1 block/CU, 8 waves.
//   - Counted schedule (R7/R11): vm8+barrier top; lgkm0+barrier WAR; stage
//     kt+2; vmcnt(0) only at kt=5. Staged traffic 126 MB (traffic-law test).
// Epilogue: rb320 = bu*4 + wr (verified R10/R11).
// ---------------------------------------------------------------------------
__global__ __launch_bounds__(512, 2) void gemm_fused_kernel(
        const unsigned char* __restrict__ ehat,
        const unsigned char* __restrict__ chat,
        const float* __restrict__ wp,
        float* __restrict__ Psum,
        float* __restrict__ T) {
    __shared__ unsigned char As[2][256 * 128];   // 2 x 32 KB
    __shared__ unsigned char Bs[2][256 * 128];   // 2 x 32 KB

    const int t    = threadIdx.x;      // 0..511
    const int lane = t & 63;
    const int c    = lane & 15;
    const int quad = lane >> 4;
    const int wid  = t >> 6;           // 0..7
    const int wr   = wid >> 1;         // row quadrant 0..3 (64 rows each)
    const int wc   = wid & 1;          // col half 0..1 (128 cols each)

    const int xcd = blockIdx.x & 7;
    const int idx = blockIdx.x >> 3;        // 0..39 per XCD
    const int bu  = xcd * 10 + (idx >> 2);  // 0..79 (256-row tiles)
    const int bj  = idx & 3;                // 0..3  (256-col tiles)
    const int m   = bu >> 2;                // 4 bu-tiles per m-slab
    const int rb4 = bu & 3;
    const int u0  = bu * 256;
    const int j0  = bj * 256;

    const unsigned char* Ag = ehat + (size_t)u0 * D_DIM;
    const unsigned char* Bg = chat + (size_t)j0 * D_DIM;

    // Staging: tile = 2048 16B chunks; thread covers ci = s*512 + t, s=0..3
    // (rows step 64; swizzle (row&7) invariant). Dest LINEAR at ci*16; the
    // global source chunk is pre-swizzled (same for A and B — symmetric).
    const int row0  = t >> 3;                                        // 0..63
    const int goff0 = row0 * D_DIM + (((t & 7) ^ (row0 & 7)) * 16);

    // Fragment bases: lane's logical chunks {quad, quad+4} of its row;
    // phys chunk = quad ^ (c&7); chunk quad+4 at byte-addr ^ 64 (bijective,
    // stays in-row since chunk^4 flips one chunk-index bit).
    const int sw     = (quad ^ (c & 7)) * 16;
    const int slotA0 = (wr * 64 + c) * 128 + sw;    // + f*2048,  f =0..3
    const int slotB0 = (wc * 128 + c) * 128 + sw;   // + jt*2048, jt=0..7

    floatx4 acc[4][8] = {};   // 128 accumulator regs (AGPR side)

    // ---- prologue: stage tiles 0 and 1 (A+B interleaved: 8 loads per tile)
    #pragma unroll
    for (int s = 0; s < 4; ++s) {
        load16_to_lds(Ag + goff0 + s * 64 * D_DIM, &As[0][s * 8192 + t * 16]);
        load16_to_lds(Bg + goff0 + s * 64 * D_DIM, &Bs[0][s * 8192 + t * 16]);
    }
    #pragma unroll
    for (int s = 0; s < 4; ++s) {
        load16_to_lds(Ag + goff0 + s * 64 * D_DIM + 128, &As[1][s * 8192 + t * 16]);
        load16_to_lds(Bg + goff0 + s * 64 * D_DIM + 128, &Bs[1][s * 8192 + t * 16]);
    }
    __builtin_amdgcn_s_waitcnt(WAIT_VM8);     // tile 0 landed; tile 1 in flight
    __builtin_amdgcn_sched_barrier(0);
    __builtin_amdgcn_s_barrier();
    __builtin_amdgcn_sched_barrier(0);

    #pragma unroll
    for (int kt = 0; kt < 6; ++kt) {
        const int cur = kt & 1;

        if (kt > 0) {
            // tile kt's 8 loads are the oldest; tile kt+1's 8 stay in flight
            if (kt < 5) __builtin_amdgcn_s_waitcnt(WAIT_VM8);
            else        __builtin_amdgcn_s_waitcnt(WAIT_VM0);
            __builtin_amdgcn_sched_barrier(0);
            __builtin_amdgcn_s_barrier();     // all threads: tile kt in LDS
            __builtin_amdgcn_sched_barrier(0);
        }

        // 4 k-subtiles of 32 bytes; ks -> (hi = (ks>>1)*64 XOR, lo = (ks&1)*8)
        #pragma unroll
        for (int ks = 0; ks < 4; ++ks) {
            const int hi = (ks >> 1) * 64;
            const int lo = (ks & 1) * 8;
            long af[4], bf[8];
            #pragma unroll
            for (int f = 0; f < 4; ++f)
                af[f] = *(const long*)(&As[cur][((slotA0 + f * 2048) ^ hi) + lo]);
            #pragma unroll
            for (int j = 0; j < 8; ++j)
                bf[j] = *(const long*)(&Bs[cur][((slotB0 + j * 2048) ^ hi) + lo]);

            __builtin_amdgcn_s_setprio(1);
            #pragma unroll
            for (int it = 0; it < 4; ++it)
                #pragma unroll
                for (int j = 0; j < 8; ++j)
                    acc[it][j] = __builtin_amdgcn_mfma_f32_16x16x32_fp8_fp8(
                        af[it], bf[j], acc[it][j], 0, 0, 0);
            __builtin_amdgcn_s_setprio(0);
        }

        if (kt < 4) {
            // WAR: all waves' ds_reads of buf[cur] retired before reuse.
            __builtin_amdgcn_s_waitcnt(WAIT_LGKM0);
            __builtin_amdgcn_sched_barrier(0);
            __builtin_amdgcn_s_barrier();
            __builtin_amdgcn_sched_barrier(0);
            const int k0 = (kt + 2) * 128;
            #pragma unroll
            for (int s = 0; s < 4; ++s) {
                load16_to_lds(Ag + goff0 + s * 64 * D_DIM + k0,
                              &As[cur][s * 8192 + t * 16]);
                load16_to_lds(Bg + goff0 + s * 64 * D_DIM + k0,
                              &Bs[cur][s * 8192 + t * 16]);
            }
            __builtin_amdgcn_sched_barrier(0);
        }
    }

    const float w = wp[0];
    const int rb320 = bu * 4 + wr;      // 64-row block index, 0..319

    // per-column fixed-offset partial: sum exp(w*(cos-1)) over the wave's 64 rows
    #pragma unroll
    for (int jt = 0; jt < 8; ++jt) {
        float sm = 0.f;
        #pragma unroll
        for (int it = 0; it < 4; ++it)
            #pragma unroll
            for (int r = 0; r < 4; ++r)
                sm += __expf(w * (acc[it][jt][r] - 1.0f));
        sm += __shfl_xor(sm, 16);
        sm += __shfl_xor(sm, 32);
        if (quad == 0)
            Psum[(size_t)rb320 * N_SPK + j0 + wc * 128 + jt * 16 + c] = sm;
    }

    // target sims: local row within m-slab == (m*1024+col)/20 (unique owner)
    #pragma unroll
    for (int it = 0; it < 4; ++it) {
        #pragma unroll
        for (int jt = 0; jt < 8; ++jt) {
            const int col = j0 + wc * 128 + jt * 16 + c;
            const int g = m * N_SPK + col;
            const int istar = g / M_UTT;
            const int rloc = rb4 * 256 + wr * 64 + it * 16 + quad * 4;
            #pragma unroll
            for (int r = 0; r < 4; ++r) {
                if (rloc + r == istar) T[g] = acc[it][jt][r];
            }
        }
    }
}

// ---------------------------------------------------------------------------
// Kernel 3: combine 16 row-block partials per (m,j) -> loss term; block sum;
// last-block writes output (ctr/accum zeroed by prep).
// term = (w*T+b) - ((w+b) + log S) = w*(T-1) - log S.
// ---------------------------------------------------------------------------
__global__ void combine_kernel(const float* __restrict__ Psum,
                               const float* __restrict__ T,
                               const float* __restrict__ wp,
                               int* __restrict__ ctr,
                               float* __restrict__ accum,
                               float* __restrict__ out) {
    const int p = blockIdx.x * 256 + threadIdx.x;
    const int m = p >> 10;
    const int j = p & 1023;
    const float w = wp[0];

    float S = 0.f;
    #pragma unroll
    for (int rb = 0; rb < 16; ++rb)
        S += Psum[(size_t)(m * 16 + rb) * N_SPK + j];
    const float term = w * (T[p] - 1.0f) - __logf(S);

    __shared__ float red[256];
    red[threadIdx.x] = term;
    __syncthreads();
    for (int o = 128; o > 0; o >>= 1) {
        if (threadIdx.x < o) red[threadIdx.x] += red[threadIdx.x + o];
        __syncthreads();
    }
    if (threadIdx.x == 0) {
        atomicAdd(accum, red[0]);
        __threadfence();
        const int old = atomicAdd(ctr, 1);
        if (old == 79) {
            const float a = atomicAdd(accum, 0.0f);   // coherent read
            out[0] = -a / (float)NM_ROWS;
        }
    }
}

// ---------------------------------------------------------------------------
extern "C" void kernel_launch(void* const* d_in, const int* in_sizes, int n_in,
                              void* d_out, int out_size, void* d_ws, size_t ws_size,
                              hipStream_t stream) {
    const float* emb = (const float*)d_in[0];
    const float* wp  = (const float*)d_in[1];
    float* out = (float*)d_out;

    char* ws = (char*)d_ws;
    //   Ehat fp8 [M][N][D] : 15,728,640  @ 0
    //   Chat fp8 [N][D]    :    786,432  @ 15,728,640
    //   Psum f32 [320][N]  :  1,310,720  @ 16,515,072
    //   T    f32 [M][N]    :     81,920  @ 17,825,792
    //   ctr i32 + accum f32:          8  @ 17,907,712
    unsigned char* ehat = (unsigned char*)(ws);
    unsigned char* chat = (unsigned char*)(ws + 15728640);
    float* Psum  = (float*)(ws + 16515072);
    float* T     = (float*)(ws + 17825792);
    int*   ctr   = (int*)  (ws + 17907712);
    float* accum = (float*)(ws + 17907716);

    prep_kernel<<<dim3(N_SPK), dim3(384), 0, stream>>>(emb, ehat, chat, ctr, accum);
    gemm_fused_kernel<<<dim3(320), dim3(512), 0, stream>>>(ehat, chat, wp, Psum, T);
    combine_kernel<<<dim3(80), dim3(256), 0, stream>>>(Psum, T, wp, ctr, accum, out);
}

// Round 14
// 130.152 us; speedup vs baseline: 1.8721x; 1.1417x over previous
//
#include <hip/hip_runtime.h>
#include <hip/hip_bf16.h>
#include <cstdint>

#define N_SPK 1024
#define M_UTT 20
#define D_DIM 768
#define NM_ROWS (N_SPK * M_UTT)   // 20480 utterances / rows

static constexpr float EPS = 1e-8f;

typedef __attribute__((ext_vector_type(4))) float floatx4;  // MFMA accumulator
typedef __attribute__((ext_vector_type(4))) int   intx4;    // 16B LDS read
typedef __attribute__((ext_vector_type(8))) int   intx8;    // 32B MFMA operand

__device__ __forceinline__ void load16_to_lds(const void* g, void* l) {
    __builtin_amdgcn_global_load_lds(
        (const __attribute__((address_space(1))) uint32_t*)g,
        (__attribute__((address_space(3))) uint32_t*)l, 16, 0, 0);
}

__device__ __forceinline__ float wave_sum(float v) {
    #pragma unroll
    for (int o = 32; o > 0; o >>= 1) v += __shfl_xor(v, o);
    return v;
}

// pack two f32 -> two OCP e4m3 bytes (low word of result)
__device__ __forceinline__ unsigned short fp8pk(float a, float b) {
    return (unsigned short)(__builtin_amdgcn_cvt_pk_fp8_f32(a, b, 0, false) & 0xFFFF);
}

// K-interleave permutation (prep-time, within each 64-byte K-block). Applied
// identically to ehat and chat; the gemm reads both operands through identical
// addressing, so this global k-bijection cancels in the MFMA dot product
// (validated empirically: absmax 0.0 in R5-R12).
__device__ __forceinline__ int kperm(int d) {
    return (d & ~63) | (((d >> 3) & 3) << 4) | (((d >> 5) & 1) << 3) | (d & 7);
}

// ---------------------------------------------------------------------------
// Kernel 1 (prep): per speaker, read emb once (float2/thread, 384 thr),
// centroid + 20 utterance norms; write FP8 e4m3 Ehat ([m][i][dp]) and Chat.
// Zero-inits ctr/accum.
// ---------------------------------------------------------------------------
__global__ __launch_bounds__(384) void prep_kernel(const float* __restrict__ emb,
                                                   unsigned char* __restrict__ ehat,
                                                   unsigned char* __restrict__ chat,
                                                   int* __restrict__ ctr,
                                                   float* __restrict__ accum) {
    const int i = blockIdx.x;      // speaker
    const int t = threadIdx.x;     // 0..383
    const int wave = t >> 6, lane = t & 63;

    if (i == 0 && t == 0) { *ctr = 0; *accum = 0.f; }

    const float2* src = (const float2*)(emb + (size_t)i * M_UTT * D_DIM);
    const int dp = kperm(t * 2);   // byte index of the fp8 pair in stored layout

    float2 v[M_UTT];
    float ss[M_UTT];
    float2 cen = {0.f, 0.f};
    #pragma unroll
    for (int m = 0; m < M_UTT; ++m) {
        const float2 x = src[m * 384 + t];
        v[m] = x;
        ss[m] = x.x * x.x + x.y * x.y;
        cen.x += x.x; cen.y += x.y;
    }
    cen.x *= (1.f / M_UTT); cen.y *= (1.f / M_UTT);
    float css = cen.x * cen.x + cen.y * cen.y;

    __shared__ float red[M_UTT + 1][6];
    #pragma unroll
    for (int m = 0; m < M_UTT; ++m) {
        const float s = wave_sum(ss[m]);
        if (lane == 0) red[m][wave] = s;
    }
    {
        const float s = wave_sum(css);
        if (lane == 0) red[M_UTT][wave] = s;
    }
    __syncthreads();

    #pragma unroll
    for (int m = 0; m < M_UTT; ++m) {
        const float tot = red[m][0] + red[m][1] + red[m][2] +
                          red[m][3] + red[m][4] + red[m][5];
        const float rn = 1.0f / fmaxf(sqrtf(tot), EPS);
        *(unsigned short*)(ehat + ((size_t)(m * N_SPK + i)) * D_DIM + dp) =
            fp8pk(v[m].x * rn, v[m].y * rn);
    }
    {
        const float tot = red[M_UTT][0] + red[M_UTT][1] + red[M_UTT][2] +
                          red[M_UTT][3] + red[M_UTT][4] + red[M_UTT][5];
        const float rn = 1.0f / fmaxf(sqrtf(tot), EPS);
        *(unsigned short*)(chat + (size_t)i * D_DIM + dp) =
            fp8pk(cen.x * rn, cen.y * rn);
    }
}

// ---------------------------------------------------------------------------
// Kernel 2 (champion, = R6, session best 129.6us): 128x128 tile, 4 waves
// (2x2 quadrants of 64x64), BK=128, 6 K-iters, 2-barrier double buffer,
// MX-scaled fp8 MFMA with unit scales.
//   Why this is the plateau (session evidence): MFMA-rate 2x (R6) neutral;
//   counted-vmcnt (R7) neutral; B off gld_lds (R8) neutral; occupancy 16 vs
//   8 waves/CU (R5 vs R6) neutral; 256^2 traffic-halving blocked by the
//   register triangle (acc 128/thread -> 1 block/CU -> tail; R9-R12).
// ---------------------------------------------------------------------------
__global__ __launch_bounds__(256, 2) void gemm_fused_kernel(
        const unsigned char* __restrict__ ehat,
        const unsigned char* __restrict__ chat,
        const float* __restrict__ wp,
        float* __restrict__ Psum,
        float* __restrict__ T) {
    __shared__ unsigned char As[2][128 * 128];   // 2 x 16 KB
    __shared__ unsigned char Bs[2][128 * 128];   // 2 x 16 KB

    const int t    = threadIdx.x;
    const int lane = t & 63;
    const int wid  = t >> 6;        // 0..3
    const int c    = lane & 15;
    const int quad = lane >> 4;
    const int wr   = wid >> 1;      // row quadrant 0..1
    const int wc   = wid & 1;       // col quadrant 0..1

    const int xcd = blockIdx.x & 7;
    const int idx = blockIdx.x >> 3;        // 0..159 per XCD
    const int bu  = xcd * 20 + (idx >> 3);  // 0..159 (128-row tiles)
    const int bj  = idx & 7;                // 0..7   (bj fastest within XCD)
    const int m   = bu >> 3;                // 8 bu-tiles per m
    const int rb8 = bu & 7;
    const int u0  = bu * 128;
    const int j0  = bj * 128;

    const unsigned char* Ag = ehat + (size_t)u0 * D_DIM;
    const unsigned char* Bg = chat + (size_t)j0 * D_DIM;

    // staging: 1024 16B chunks per operand tile; ci = s*256 + t, s=0..3.
    // Dest LINEAR at ci*16 (wave-uniform base + lane*16 by construction);
    // global source chunk pre-swizzled: phys p=ci&7 holds logical l=p^(row&7).
    int goff[4];
    #pragma unroll
    for (int s = 0; s < 4; ++s) {
        const int ci  = s * 256 + t;
        const int row = ci >> 3;                    // 0..127
        const int l   = (ci & 7) ^ (row & 7);
        goff[s] = row * D_DIM + l * 16;
    }

    // fragment read: lane wants logical chunks {quad, quad+4} of its row.
    // phys0 = quad ^ (row&7) (row&7 == c&7); second half at addr ^ 64.
    int slotA[4], slotB[4];   // [frag]
    #pragma unroll
    for (int f = 0; f < 4; ++f) {
        const int rA = wr * 64 + f * 16 + c;
        const int rB = wc * 64 + f * 16 + c;
        slotA[f] = rA * 128 + ((quad ^ (c & 7)) * 16);
        slotB[f] = rB * 128 + ((quad ^ (c & 7)) * 16);
    }

    floatx4 acc[4][4] = {};

    // prologue: stage K-tile 0 into buf 0
    #pragma unroll
    for (int s = 0; s < 4; ++s) {
        load16_to_lds(Ag + goff[s], &As[0][(s * 256 + t) * 16]);
        load16_to_lds(Bg + goff[s], &Bs[0][(s * 256 + t) * 16]);
    }
    __syncthreads();   // compiler emits vmcnt(0) drain before s_barrier

    #pragma unroll
    for (int kt = 0; kt < 6; ++kt) {
        const int cur = kt & 1;
        const int nxt = cur ^ 1;

        if (kt < 5) {
            const int k0 = (kt + 1) * 128;
            #pragma unroll
            for (int s = 0; s < 4; ++s) {
                load16_to_lds(Ag + goff[s] + k0, &As[nxt][(s * 256 + t) * 16]);
                load16_to_lds(Bg + goff[s] + k0, &Bs[nxt][(s * 256 + t) * 16]);
            }
        }

        intx8 av[4], bv[4];
        #pragma unroll
        for (int f = 0; f < 4; ++f) {
            const intx4 lo = *(const intx4*)(&As[cur][slotA[f]]);
            const intx4 hi = *(const intx4*)(&As[cur][slotA[f] ^ 64]);
            av[f] = __builtin_shufflevector(lo, hi, 0, 1, 2, 3, 4, 5, 6, 7);
        }
        #pragma unroll
        for (int f = 0; f < 4; ++f) {
            const intx4 lo = *(const intx4*)(&Bs[cur][slotB[f]]);
            const intx4 hi = *(const intx4*)(&Bs[cur][slotB[f] ^ 64]);
            bv[f] = __builtin_shufflevector(lo, hi, 0, 1, 2, 3, 4, 5, 6, 7);
        }

        #pragma unroll
        for (int it = 0; it < 4; ++it)
            #pragma unroll
            for (int jt = 0; jt < 4; ++jt)
                acc[it][jt] = __builtin_amdgcn_mfma_scale_f32_16x16x128_f8f6f4(
                    av[it], bv[jt], acc[it][jt],
                    0, 0,                      // cbsz=fp8(e4m3), blgp=fp8(e4m3)
                    0, 0x7F7F7F7F,             // A scales: e8m0 1.0
                    0, 0x7F7F7F7F);            // B scales: e8m0 1.0

        if (kt < 5) __syncthreads();   // drains vmcnt (next tile landed) + sync
    }

    const float w = wp[0];
    const int rb320 = bu * 2 + wr;      // 64-row block index, 0..319

    // per-column fixed-offset partial: sum exp(w*(cos-1)) over quadrant's 64 rows
    #pragma unroll
    for (int jt = 0; jt < 4; ++jt) {
        float sm = 0.f;
        #pragma unroll
        for (int it = 0; it < 4; ++it)
            #pragma unroll
            for (int r = 0; r < 4; ++r)
                sm += __expf(w * (acc[it][jt][r] - 1.0f));
        sm += __shfl_xor(sm, 16);
        sm += __shfl_xor(sm, 32);
        if (quad == 0)
            Psum[(size_t)rb320 * N_SPK + j0 + wc * 64 + jt * 16 + c] = sm;
    }

    // target sims: local row within m-slab == (m*1024+col)/20 (unique owner)
    #pragma unroll
    for (int it = 0; it < 4; ++it) {
        #pragma unroll
        for (int jt = 0; jt < 4; ++jt) {
            const int col = j0 + wc * 64 + jt * 16 + c;
            const int g = m * N_SPK + col;
            const int istar = g / M_UTT;
            const int rloc = rb8 * 128 + wr * 64 + it * 16 + quad * 4;
            #pragma unroll
            for (int r = 0; r < 4; ++r) {
                if (rloc + r == istar) T[g] = acc[it][jt][r];
            }
        }
    }
}

// ---------------------------------------------------------------------------
// Kernel 3: combine 16 row-block partials per (m,j) -> loss term; block sum;
// last-block writes output (ctr/accum zeroed by prep).
// term = (w*T+b) - ((w+b) + log S) = w*(T-1) - log S.
// ---------------------------------------------------------------------------
__global__ void combine_kernel(const float* __restrict__ Psum,
                               const float* __restrict__ T,
                               const float* __restrict__ wp,
                               int* __restrict__ ctr,
                               float* __restrict__ accum,
                               float* __restrict__ out) {
    const int p = blockIdx.x * 256 + threadIdx.x;
    const int m = p >> 10;
    const int j = p & 1023;
    const float w = wp[0];

    float S = 0.f;
    #pragma unroll
    for (int rb = 0; rb < 16; ++rb)
        S += Psum[(size_t)(m * 16 + rb) * N_SPK + j];
    const float term = w * (T[p] - 1.0f) - __logf(S);

    __shared__ float red[256];
    red[threadIdx.x] = term;
    __syncthreads();
    for (int o = 128; o > 0; o >>= 1) {
        if (threadIdx.x < o) red[threadIdx.x] += red[threadIdx.x + o];
        __syncthreads();
    }
    if (threadIdx.x == 0) {
        atomicAdd(accum, red[0]);
        __threadfence();
        const int old = atomicAdd(ctr, 1);
        if (old == 79) {
            const float a = atomicAdd(accum, 0.0f);   // coherent read
            out[0] = -a / (float)NM_ROWS;
        }
    }
}

// ---------------------------------------------------------------------------
extern "C" void kernel_launch(void* const* d_in, const int* in_sizes, int n_in,
                              void* d_out, int out_size, void* d_ws, size_t ws_size,
                              hipStream_t stream) {
    const float* emb = (const float*)d_in[0];
    const float* wp  = (const float*)d_in[1];
    float* out = (float*)d_out;

    char* ws = (char*)d_ws;
    //   Ehat fp8 [M][N][D] : 15,728,640  @ 0
    //   Chat fp8 [N][D]    :    786,432  @ 15,728,640
    //   Psum f32 [320][N]  :  1,310,720  @ 16,515,072
    //   T    f32 [M][N]    :     81,920  @ 17,825,792
    //   ctr i32 + accum f32:          8  @ 17,907,712
    unsigned char* ehat = (unsigned char*)(ws);
    unsigned char* chat = (unsigned char*)(ws + 15728640);
    float* Psum  = (float*)(ws + 16515072);
    float* T     = (float*)(ws + 17825792);
    int*   ctr   = (int*)  (ws + 17907712);
    float* accum = (float*)(ws + 17907716);

    prep_kernel<<<dim3(N_SPK), dim3(384), 0, stream>>>(emb, ehat, chat, ctr, accum);
    gemm_fused_kernel<<<dim3(1280), dim3(256), 0, stream>>>(ehat, chat, wp, Psum, T);
    combine_kernel<<<dim3(80), dim3(256), 0, stream>>>(Psum, T, wp, ctr, accum, out);
}